// Round 4
// baseline (178.243 us; speedup 1.0000x reference)
//
#include <hip/hip_runtime.h>
#include <cstdint>
#include <cstddef>

constexpr int kN = 2048;   // layer size (power of 2 -> cheap mod)
constexpr int kB = 4096;   // batch
constexpr int kR = 4;      // displacement rank

typedef __attribute__((ext_vector_type(4))) float f32x4;
typedef __attribute__((ext_vector_type(8))) short short8;
typedef __attribute__((ext_vector_type(8))) unsigned short ushort8;

__device__ __forceinline__ unsigned short f2bf(float f) {
  unsigned u = __float_as_uint(f);
  u += 0x7FFFu + ((u >> 16) & 1u);   // round-to-nearest-even
  return (unsigned short)(u >> 16);
}

__device__ __forceinline__ void gload_lds16(const void* g, void* l) {
  __builtin_amdgcn_global_load_lds(
      (const __attribute__((address_space(1))) void*)g,
      (__attribute__((address_space(3))) void*)l, 16, 0, 0);
}

// ---------------- kernel 1 (fused): cast x->bf16  +  per-diagonal prefix scan ----------------
__global__ void prep_kernel(const float* __restrict__ x,
                            const float* __restrict__ G,
                            const float* __restrict__ H,
                            unsigned short* __restrict__ xb,
                            unsigned short* __restrict__ Dp) {
  __shared__ float wsum[4];
  const int tid = threadIdx.x;

  if (blockIdx.x < (kB * kN) / (256 * 8)) {
    const int t = blockIdx.x * 256 + tid;
    const float4* xv = (const float4*)x;
    float4 a = xv[t * 2];
    float4 b = xv[t * 2 + 1];
    ushort8 o;
    o[0] = f2bf(a.x); o[1] = f2bf(a.y); o[2] = f2bf(a.z); o[3] = f2bf(a.w);
    o[4] = f2bf(b.x); o[5] = f2bf(b.y); o[6] = f2bf(b.z); o[7] = f2bf(b.w);
    *(ushort8*)(xb + (size_t)t * 8) = o;
    return;
  }

  const int d = blockIdx.x - (kB * kN) / (256 * 8);
  const int lane = tid & 63, wave = tid >> 6;
  const int v0 = tid * 8;

  float loc[8];
  float run = 0.f;
#pragma unroll
  for (int jj = 0; jj < 8; ++jj) {
    const int v = v0 + jj;
    float q = 0.f;
#pragma unroll
    for (int t = 0; t < kR; ++t)
      q += G[t * kN + ((v + d) & (kN - 1))] * H[t * kN + v];
    run += q;
    loc[jj] = run;                      // inclusive within thread
  }

  float incl = run;
#pragma unroll
  for (int off = 1; off < 64; off <<= 1) {
    float tv = __shfl_up(incl, off, 64);
    if (lane >= off) incl += tv;
  }
  if (lane == 63) wsum[wave] = incl;
  __syncthreads();
  float woff = 0.f, total = 0.f;
#pragma unroll
  for (int w = 0; w < 4; ++w) {
    const float s = wsum[w];
    total += s;
    if (w < wave) woff += s;
  }
  const float exc = woff + incl - run;  // exclusive prefix for this thread

  ushort8 o;
#pragma unroll
  for (int jj = 0; jj < 8; ++jj)
    o[jj] = f2bf(2.f * (exc + loc[jj]) - total);
  *(ushort8*)(Dp + (size_t)d * kN + v0) = o;
}

// ---------------- kernel 2: diagonal -> row-major transpose ----------------
__global__ void build_M_kernel(const unsigned short* __restrict__ Dp,
                               unsigned short* __restrict__ Mb) {
  __shared__ unsigned short lds[128][64];
  const int tid = threadIdx.x;
  const int i0 = blockIdx.y * 64, j0 = blockIdx.x * 64;
  const int delta0 = (i0 - j0 - 63) & (kN - 1);
#pragma unroll
  for (int it = 0; it < 32; ++it) {
    const int lin = it * 256 + tid;
    const int dd = lin >> 6, jj = lin & 63;
    lds[dd][jj] = Dp[(size_t)((delta0 + dd) & (kN - 1)) * kN + j0 + jj];
  }
  __syncthreads();
#pragma unroll
  for (int it = 0; it < 16; ++it) {
    const int lin = it * 256 + tid;
    const int ii = lin >> 6, jj = lin & 63;
    Mb[(size_t)(i0 + ii) * kN + j0 + jj] = lds[ii - jj + 63][jj];
  }
}

// ---------------- kernel 3: out = x @ M^T  (bf16 MFMA, min-2ph dbuf, 3 blocks/CU) ----------------
// BM=128 x BN=64, BK=64, 4 waves (2x2), per-wave 64x32 -> 16 MFMA / K-tile / wave.
// 48 KB LDS -> 3 blocks/CU (m97/m114 mechanism: desynced blocks cover barrier drains).
// Grid 32x32=1024 = 4 requested/CU. Full-row XOR swizzle (chunk ^ row&7): 2-way = free.
__global__ __launch_bounds__(256, 3) void gemm_kernel(
    const unsigned short* __restrict__ A,
    const unsigned short* __restrict__ Bt,
    float* __restrict__ C) {
  __shared__ unsigned short As[2][8192];   // 2 x 16 KB  (128 rows x 64 k)
  __shared__ unsigned short Bs[2][4096];   // 2 x  8 KB  ( 64 rows x 64 k)

  const int tid = threadIdx.x;
  const int lane = tid & 63, wave = tid >> 6;
  const int wr = wave >> 1, wc = wave & 1;          // 2x2 waves: 64(m) x 32(n) each
  const int r16 = lane & 15, kg = lane >> 4;

  // T1 bijective XCD swizzle (1024 blocks % 8 == 0)
  const int flat = blockIdx.y * gridDim.x + blockIdx.x;
  const int swz = (flat & 7) * 128 + (flat >> 3);
  const int by = swz >> 5, bx = swz & 31;
  const int row0 = by * 128, col0 = bx * 64;

  const unsigned short* Abase = A + (size_t)row0 * kN;
  const unsigned short* Bbase = Bt + (size_t)col0 * kN;

  f32x4 acc[4][2] = {};

  // stage: LDS slot = linear chunk index (gload_lds needs linear dest);
  // global source pre-swizzled with the same involution used on the read side.
  auto stageA = [&](const unsigned short* src, unsigned short* dst) {
#pragma unroll
    for (int i = 0; i < 4; ++i) {
      const int slot = i * 256 + tid;           // 0..1023 = 128 rows x 8 chunks
      const int r = slot >> 3, cl = slot & 7;
      gload_lds16((const char*)src + r * (kN * 2) + ((cl ^ (r & 7)) << 4),
                  (char*)dst + slot * 16);
    }
  };
  auto stageB = [&](const unsigned short* src, unsigned short* dst) {
#pragma unroll
    for (int i = 0; i < 2; ++i) {
      const int slot = i * 256 + tid;           // 0..511 = 64 rows x 8 chunks
      const int r = slot >> 3, cl = slot & 7;
      gload_lds16((const char*)src + r * (kN * 2) + ((cl ^ (r & 7)) << 4),
                  (char*)dst + slot * 16);
    }
  };

  // prologue: stage tile 0 into buffer 0
  stageA(Abase, As[0]);
  stageB(Bbase, Bs[0]);
  __syncthreads();

  for (int t = 0; t < kN / 64; ++t) {
    const int cur = t & 1;
    if (t < kN / 64 - 1) {                 // issue next tile's loads FIRST
      stageA(Abase + (t + 1) * 64, As[cur ^ 1]);
      stageB(Bbase + (t + 1) * 64, Bs[cur ^ 1]);
    }
    __builtin_amdgcn_sched_barrier(0);     // keep load-issue ahead of compute

    const char* abuf = (const char*)As[cur];
    const char* bbuf = (const char*)Bs[cur];
#pragma unroll
    for (int s = 0; s < 2; ++s) {
      short8 af[4], bf[2];
#pragma unroll
      for (int mt = 0; mt < 4; ++mt) {
        const int row = wr * 64 + mt * 16 + r16;
        af[mt] = *(const short8*)(abuf + row * 128 + (((s * 4 + kg) ^ (row & 7)) << 4));
      }
#pragma unroll
      for (int nt = 0; nt < 2; ++nt) {
        const int row = wc * 32 + nt * 16 + r16;
        bf[nt] = *(const short8*)(bbuf + row * 128 + (((s * 4 + kg) ^ (row & 7)) << 4));
      }
#pragma unroll
      for (int mt = 0; mt < 4; ++mt)
#pragma unroll
        for (int nt = 0; nt < 2; ++nt)
          acc[mt][nt] = __builtin_amdgcn_mfma_f32_16x16x32_bf16(
              af[mt], bf[nt], acc[mt][nt], 0, 0, 0);
    }

    __syncthreads();                       // one drain per K-tile
  }

  // epilogue: D row = (lane>>4)*4 + reg, col = lane&15 (verified layout)
#pragma unroll
  for (int mt = 0; mt < 4; ++mt)
#pragma unroll
    for (int nt = 0; nt < 2; ++nt) {
      const int r = row0 + wr * 64 + mt * 16 + kg * 4;
      const int c = col0 + wc * 32 + nt * 16 + r16;
#pragma unroll
      for (int j = 0; j < 4; ++j)
        C[(size_t)(r + j) * kN + c] = acc[mt][nt][j];
    }
}

extern "C" void kernel_launch(void* const* d_in, const int* in_sizes, int n_in,
                              void* d_out, int out_size, void* d_ws, size_t ws_size,
                              hipStream_t stream) {
  const float* x = (const float*)d_in[0];
  const float* G = (const float*)d_in[1];
  const float* H = (const float*)d_in[2];
  float* out = (float*)d_out;

  char* ws = (char*)d_ws;
  unsigned short* Mb = (unsigned short*)ws;                      // 8 MB  bf16 M[i][j]
  unsigned short* xb = (unsigned short*)(ws + (8u << 20));       // 16 MB bf16 x
  unsigned short* Dp = (unsigned short*)(ws + (24u << 20));      // 8 MB  bf16 diag-major

  const int cast_blocks = (kB * kN) / (256 * 8);                 // 4096
  prep_kernel<<<dim3(cast_blocks + kN), dim3(256), 0, stream>>>(x, G, H, xb, Dp);
  build_M_kernel<<<dim3(kN / 64, kN / 64), dim3(256), 0, stream>>>(Dp, Mb);
  gemm_kernel<<<dim3(kN / 64, kB / 128), dim3(256), 0, stream>>>(xb, Mb, out);
}

// Round 5
// 171.935 us; speedup vs baseline: 1.0367x; 1.0367x over previous
//
#include <hip/hip_runtime.h>
#include <cstdint>
#include <cstddef>

constexpr int kN = 2048;   // layer size (power of 2 -> cheap mod)
constexpr int kB = 4096;   // batch
constexpr int kR = 4;      // displacement rank

typedef __attribute__((ext_vector_type(4))) float f32x4;
typedef __attribute__((ext_vector_type(8))) short short8;
typedef __attribute__((ext_vector_type(8))) unsigned short ushort8;

__device__ __forceinline__ unsigned short f2bf(float f) {
  unsigned u = __float_as_uint(f);
  u += 0x7FFFu + ((u >> 16) & 1u);   // round-to-nearest-even
  return (unsigned short)(u >> 16);
}

__device__ __forceinline__ void gload_lds16(const void* g, void* l) {
  __builtin_amdgcn_global_load_lds(
      (const __attribute__((address_space(1))) void*)g,
      (__attribute__((address_space(3))) void*)l, 16, 0, 0);
}

// ---------------- kernel 1 (fused): cast x->bf16  +  per-diagonal prefix scan ----------------
__global__ void prep_kernel(const float* __restrict__ x,
                            const float* __restrict__ G,
                            const float* __restrict__ H,
                            unsigned short* __restrict__ xb,
                            unsigned short* __restrict__ Dp) {
  __shared__ float wsum[4];
  const int tid = threadIdx.x;

  if (blockIdx.x < (kB * kN) / (256 * 8)) {
    const int t = blockIdx.x * 256 + tid;
    const float4* xv = (const float4*)x;
    float4 a = xv[t * 2];
    float4 b = xv[t * 2 + 1];
    ushort8 o;
    o[0] = f2bf(a.x); o[1] = f2bf(a.y); o[2] = f2bf(a.z); o[3] = f2bf(a.w);
    o[4] = f2bf(b.x); o[5] = f2bf(b.y); o[6] = f2bf(b.z); o[7] = f2bf(b.w);
    *(ushort8*)(xb + (size_t)t * 8) = o;
    return;
  }

  const int d = blockIdx.x - (kB * kN) / (256 * 8);
  const int lane = tid & 63, wave = tid >> 6;
  const int v0 = tid * 8;

  float loc[8];
  float run = 0.f;
#pragma unroll
  for (int jj = 0; jj < 8; ++jj) {
    const int v = v0 + jj;
    float q = 0.f;
#pragma unroll
    for (int t = 0; t < kR; ++t)
      q += G[t * kN + ((v + d) & (kN - 1))] * H[t * kN + v];
    run += q;
    loc[jj] = run;                      // inclusive within thread
  }

  float incl = run;
#pragma unroll
  for (int off = 1; off < 64; off <<= 1) {
    float tv = __shfl_up(incl, off, 64);
    if (lane >= off) incl += tv;
  }
  if (lane == 63) wsum[wave] = incl;
  __syncthreads();
  float woff = 0.f, total = 0.f;
#pragma unroll
  for (int w = 0; w < 4; ++w) {
    const float s = wsum[w];
    total += s;
    if (w < wave) woff += s;
  }
  const float exc = woff + incl - run;  // exclusive prefix for this thread

  ushort8 o;
#pragma unroll
  for (int jj = 0; jj < 8; ++jj)
    o[jj] = f2bf(2.f * (exc + loc[jj]) - total);
  *(ushort8*)(Dp + (size_t)d * kN + v0) = o;
}

// ---------------- kernel 2: diagonal -> row-major transpose ----------------
__global__ void build_M_kernel(const unsigned short* __restrict__ Dp,
                               unsigned short* __restrict__ Mb) {
  __shared__ unsigned short lds[128][64];
  const int tid = threadIdx.x;
  const int i0 = blockIdx.y * 64, j0 = blockIdx.x * 64;
  const int delta0 = (i0 - j0 - 63) & (kN - 1);
#pragma unroll
  for (int it = 0; it < 32; ++it) {
    const int lin = it * 256 + tid;
    const int dd = lin >> 6, jj = lin & 63;
    lds[dd][jj] = Dp[(size_t)((delta0 + dd) & (kN - 1)) * kN + j0 + jj];
  }
  __syncthreads();
#pragma unroll
  for (int it = 0; it < 16; ++it) {
    const int lin = it * 256 + tid;
    const int ii = lin >> 6, jj = lin & 63;
    Mb[(size_t)(i0 + ii) * kN + j0 + jj] = lds[ii - jj + 63][jj];
  }
}

// ---------------- kernel 3: out = x @ M^T ----------------
// BM=256 x BN=128, BK=64, 512 thr (8 waves, 4x2 -> per-wave 64x64).
// Grid 16x16 = 256 blocks = 1/CU, 2 waves/SIMD.
// Depth-2 pipeline, 3 LDS buffers (144 KB): during tile t issue tile t+2's
// loads; tile head waits vmcnt(6) only (t+1's 6 loads stay in flight across
// the barrier -- T4 counted vmcnt). 4 phases/tile, setprio around MFMA (T5).
// XOR chunk-swizzle (chunk ^ row&7), pre-swizzled global source (rule #21).
__global__ __launch_bounds__(512, 1) void gemm_kernel(
    const unsigned short* __restrict__ A,
    const unsigned short* __restrict__ Bt,
    float* __restrict__ C) {
  __shared__ unsigned short As[3][256 * 64];   // 3 x 32 KB
  __shared__ unsigned short Bs[3][128 * 64];   // 3 x 16 KB   (total 144 KB)

  const int tid = threadIdx.x;
  const int lane = tid & 63, wave = tid >> 6;
  const int wr = wave >> 1, wc = wave & 1;      // 4x2 waves: 64(m) x 64(n) each
  const int r16 = lane & 15, kg = lane >> 4;

  // T1 bijective XCD swizzle (256 blocks % 8 == 0)
  const int flat = blockIdx.y * gridDim.x + blockIdx.x;
  const int swz = (flat & 7) * 32 + (flat >> 3);
  const int by = swz >> 4, bx = swz & 15;
  const int row0 = by * 256, col0 = bx * 128;

  const char* Abase = (const char*)(A + (size_t)row0 * kN);
  const char* Bbase = (const char*)(Bt + (size_t)col0 * kN);

  // per-thread staging source offsets (row-fixed, chunk pre-swizzled)
  int aoff[4], boff[2];
#pragma unroll
  for (int i = 0; i < 4; ++i) {
    const int slot = i * 512 + tid;          // 0..2047 = 256 rows x 8 chunks
    const int r = slot >> 3, cl = slot & 7;
    aoff[i] = r * (kN * 2) + ((cl ^ (r & 7)) << 4);
  }
#pragma unroll
  for (int i = 0; i < 2; ++i) {
    const int slot = i * 512 + tid;          // 0..1023 = 128 rows x 8 chunks
    const int r = slot >> 3, cl = slot & 7;
    boff[i] = r * (kN * 2) + ((cl ^ (r & 7)) << 4);
  }

  f32x4 acc[4][4] = {};

#define STAGE_A(kt, buf, i) \
  gload_lds16(Abase + aoff[i] + (kt) * 128, (char*)As[buf] + ((i) * 512 + tid) * 16)
#define STAGE_B(kt, buf, i) \
  gload_lds16(Bbase + boff[i] + (kt) * 128, (char*)Bs[buf] + ((i) * 512 + tid) * 16)

  // prologue: stage tiles 0 and 1 (12 loads in flight)
#pragma unroll
  for (int i = 0; i < 4; ++i) STAGE_A(0, 0, i);
#pragma unroll
  for (int i = 0; i < 2; ++i) STAGE_B(0, 0, i);
#pragma unroll
  for (int i = 0; i < 4; ++i) STAGE_A(1, 1, i);
#pragma unroll
  for (int i = 0; i < 2; ++i) STAGE_B(1, 1, i);

  for (int t = 0; t < kN / 64; ++t) {
    const int cur = t % 3, nxt = (t + 2) % 3;
    const bool more = (t + 2) < kN / 64;

    // ---- tile head: counted wait (T4) + barrier ----
    if (t < kN / 64 - 1) asm volatile("s_waitcnt vmcnt(6)" ::: "memory");
    else                 asm volatile("s_waitcnt vmcnt(0)" ::: "memory");
    __builtin_amdgcn_s_barrier();

    const char* abuf = (const char*)As[cur];
    const char* bbuf = (const char*)Bs[cur];

    // B fragments for the whole tile (covered by phase-0 lgkmcnt)
    short8 bfr[4][2];
#pragma unroll
    for (int nt = 0; nt < 4; ++nt) {
      const int brow = wc * 64 + nt * 16 + r16;
#pragma unroll
      for (int s = 0; s < 2; ++s)
        bfr[nt][s] = *(const short8*)(bbuf + brow * 128 + (((s * 4 + kg) ^ (brow & 7)) << 4));
    }

#define PHASE(mt, STAGES)                                                       \
    {                                                                           \
      const int arow = wr * 64 + (mt) * 16 + r16;                               \
      short8 af0 = *(const short8*)(abuf + arow * 128 + (((kg) ^ (arow & 7)) << 4));       \
      short8 af1 = *(const short8*)(abuf + arow * 128 + (((4 + kg) ^ (arow & 7)) << 4));   \
      STAGES;                                                                   \
      __builtin_amdgcn_s_barrier();                                             \
      asm volatile("s_waitcnt lgkmcnt(0)" ::: "memory");                        \
      __builtin_amdgcn_sched_barrier(0);                                        \
      __builtin_amdgcn_s_setprio(1);                                            \
      acc[mt][0] = __builtin_amdgcn_mfma_f32_16x16x32_bf16(af0, bfr[0][0], acc[mt][0], 0, 0, 0); \
      acc[mt][0] = __builtin_amdgcn_mfma_f32_16x16x32_bf16(af1, bfr[0][1], acc[mt][0], 0, 0, 0); \
      acc[mt][1] = __builtin_amdgcn_mfma_f32_16x16x32_bf16(af0, bfr[1][0], acc[mt][1], 0, 0, 0); \
      acc[mt][1] = __builtin_amdgcn_mfma_f32_16x16x32_bf16(af1, bfr[1][1], acc[mt][1], 0, 0, 0); \
      acc[mt][2] = __builtin_amdgcn_mfma_f32_16x16x32_bf16(af0, bfr[2][0], acc[mt][2], 0, 0, 0); \
      acc[mt][2] = __builtin_amdgcn_mfma_f32_16x16x32_bf16(af1, bfr[2][1], acc[mt][2], 0, 0, 0); \
      acc[mt][3] = __builtin_amdgcn_mfma_f32_16x16x32_bf16(af0, bfr[3][0], acc[mt][3], 0, 0, 0); \
      acc[mt][3] = __builtin_amdgcn_mfma_f32_16x16x32_bf16(af1, bfr[3][1], acc[mt][3], 0, 0, 0); \
      __builtin_amdgcn_s_setprio(0);                                            \
    }

    PHASE(0, if (more) { STAGE_A(t + 2, nxt, 0); STAGE_A(t + 2, nxt, 1); });
    PHASE(1, if (more) { STAGE_A(t + 2, nxt, 2); STAGE_A(t + 2, nxt, 3); });
    PHASE(2, if (more) { STAGE_B(t + 2, nxt, 0); STAGE_B(t + 2, nxt, 1); });
    PHASE(3, );
#undef PHASE
  }

  // epilogue: D row = (lane>>4)*4 + reg, col = lane&15 (verified layout)
#pragma unroll
  for (int mt = 0; mt < 4; ++mt)
#pragma unroll
    for (int nt = 0; nt < 4; ++nt) {
      const int r = row0 + wr * 64 + mt * 16 + kg * 4;
      const int c = col0 + wc * 64 + nt * 16 + r16;
#pragma unroll
      for (int j = 0; j < 4; ++j)
        C[(size_t)(r + j) * kN + c] = acc[mt][nt][j];
    }
}

extern "C" void kernel_launch(void* const* d_in, const int* in_sizes, int n_in,
                              void* d_out, int out_size, void* d_ws, size_t ws_size,
                              hipStream_t stream) {
  const float* x = (const float*)d_in[0];
  const float* G = (const float*)d_in[1];
  const float* H = (const float*)d_in[2];
  float* out = (float*)d_out;

  char* ws = (char*)d_ws;
  unsigned short* Mb = (unsigned short*)ws;                      // 8 MB  bf16 M[i][j]
  unsigned short* xb = (unsigned short*)(ws + (8u << 20));       // 16 MB bf16 x
  unsigned short* Dp = (unsigned short*)(ws + (24u << 20));      // 8 MB  bf16 diag-major

  const int cast_blocks = (kB * kN) / (256 * 8);                 // 4096
  prep_kernel<<<dim3(cast_blocks + kN), dim3(256), 0, stream>>>(x, G, H, xb, Dp);
  build_M_kernel<<<dim3(kN / 64, kN / 64), dim3(256), 0, stream>>>(Dp, Mb);
  gemm_kernel<<<dim3(kN / 128, kB / 256), dim3(512), 0, stream>>>(xb, Mb, out);
}

// Round 6
// 171.847 us; speedup vs baseline: 1.0372x; 1.0005x over previous
//
#include <hip/hip_runtime.h>
#include <cstdint>
#include <cstddef>

constexpr int kN = 2048;   // layer size (power of 2 -> cheap mod)
constexpr int kB = 4096;   // batch
constexpr int kR = 4;      // displacement rank

typedef __attribute__((ext_vector_type(4))) float f32x4;
typedef __attribute__((ext_vector_type(8))) short short8;
typedef __attribute__((ext_vector_type(8))) unsigned short ushort8;

__device__ __forceinline__ unsigned short f2bf(float f) {
  unsigned u = __float_as_uint(f);
  u += 0x7FFFu + ((u >> 16) & 1u);   // round-to-nearest-even
  return (unsigned short)(u >> 16);
}

__device__ __forceinline__ void gload_lds16(const void* g, void* l) {
  __builtin_amdgcn_global_load_lds(
      (const __attribute__((address_space(1))) void*)g,
      (__attribute__((address_space(3))) void*)l, 16, 0, 0);
}

// ---------------- kernel 1 (fused): cast x->bf16  +  per-diagonal prefix scan ----------------
__global__ void prep_kernel(const float* __restrict__ x,
                            const float* __restrict__ G,
                            const float* __restrict__ H,
                            unsigned short* __restrict__ xb,
                            unsigned short* __restrict__ Dp) {
  __shared__ float wsum[4];
  const int tid = threadIdx.x;

  if (blockIdx.x < (kB * kN) / (256 * 8)) {
    const int t = blockIdx.x * 256 + tid;
    const float4* xv = (const float4*)x;
    float4 a = xv[t * 2];
    float4 b = xv[t * 2 + 1];
    ushort8 o;
    o[0] = f2bf(a.x); o[1] = f2bf(a.y); o[2] = f2bf(a.z); o[3] = f2bf(a.w);
    o[4] = f2bf(b.x); o[5] = f2bf(b.y); o[6] = f2bf(b.z); o[7] = f2bf(b.w);
    *(ushort8*)(xb + (size_t)t * 8) = o;
    return;
  }

  const int d = blockIdx.x - (kB * kN) / (256 * 8);
  const int lane = tid & 63, wave = tid >> 6;
  const int v0 = tid * 8;

  float loc[8];
  float run = 0.f;
#pragma unroll
  for (int jj = 0; jj < 8; ++jj) {
    const int v = v0 + jj;
    float q = 0.f;
#pragma unroll
    for (int t = 0; t < kR; ++t)
      q += G[t * kN + ((v + d) & (kN - 1))] * H[t * kN + v];
    run += q;
    loc[jj] = run;                      // inclusive within thread
  }

  float incl = run;
#pragma unroll
  for (int off = 1; off < 64; off <<= 1) {
    float tv = __shfl_up(incl, off, 64);
    if (lane >= off) incl += tv;
  }
  if (lane == 63) wsum[wave] = incl;
  __syncthreads();
  float woff = 0.f, total = 0.f;
#pragma unroll
  for (int w = 0; w < 4; ++w) {
    const float s = wsum[w];
    total += s;
    if (w < wave) woff += s;
  }
  const float exc = woff + incl - run;  // exclusive prefix for this thread

  ushort8 o;
#pragma unroll
  for (int jj = 0; jj < 8; ++jj)
    o[jj] = f2bf(2.f * (exc + loc[jj]) - total);
  *(ushort8*)(Dp + (size_t)d * kN + v0) = o;
}

// ---------------- kernel 2: diagonal -> row-major transpose ----------------
__global__ void build_M_kernel(const unsigned short* __restrict__ Dp,
                               unsigned short* __restrict__ Mb) {
  __shared__ unsigned short lds[128][64];
  const int tid = threadIdx.x;
  const int i0 = blockIdx.y * 64, j0 = blockIdx.x * 64;
  const int delta0 = (i0 - j0 - 63) & (kN - 1);
#pragma unroll
  for (int it = 0; it < 32; ++it) {
    const int lin = it * 256 + tid;
    const int dd = lin >> 6, jj = lin & 63;
    lds[dd][jj] = Dp[(size_t)((delta0 + dd) & (kN - 1)) * kN + j0 + jj];
  }
  __syncthreads();
#pragma unroll
  for (int it = 0; it < 16; ++it) {
    const int lin = it * 256 + tid;
    const int ii = lin >> 6, jj = lin & 63;
    Mb[(size_t)(i0 + ii) * kN + j0 + jj] = lds[ii - jj + 63][jj];
  }
}

// ---------------- kernel 3: out = x @ M^T ----------------
// R3 geometry (BM=BN=128, 4 waves 2x2, per-wave 64x64) -- best measured (680 TF)
// -- with the full-drain removed: BK=32, THREE LDS buffers (48 KB), depth-2
// prefetch, raw s_barrier + counted vmcnt(4) at tile head (T4/m139 pattern).
// Stages issued AFTER the head barrier (all waves past barrier => all prior
// readers of the target buffer done -- R5-proven WAR safety). T5 setprio
// around MFMA. ds_reads stay C++-level (compiler lgkm, rule-18 safe).
__global__ __launch_bounds__(256, 2) void gemm_kernel(
    const unsigned short* __restrict__ A,
    const unsigned short* __restrict__ Bt,
    float* __restrict__ C) {
  __shared__ unsigned short As[3][128 * 32];   // 3 x 8 KB
  __shared__ unsigned short Bs[3][128 * 32];   // 3 x 8 KB  (48 KB total)

  const int tid = threadIdx.x;
  const int lane = tid & 63, wave = tid >> 6;
  const int wr = wave >> 1, wc = wave & 1;      // 2x2 waves, 64x64 each
  const int r16 = lane & 15, kg = lane >> 4;

  // T1 bijective XCD swizzle (512 blocks % 8 == 0)
  const int flat = blockIdx.y * gridDim.x + blockIdx.x;
  const int swz = (flat & 7) * 64 + (flat >> 3);
  const int by = swz >> 4, bx = swz & 15;
  const int row0 = by * 128, col0 = bx * 128;

  const char* Abase = (const char*)(A + (size_t)row0 * kN);
  const char* Bbase = (const char*)(Bt + (size_t)col0 * kN);

  // per-thread staging source offsets: slot = row*4 + chunk (128 rows x 4 chunks
  // of 16B per 32-k tile); chunk pre-swizzled with (row&3) involution (rule #21)
  int goff[2];
#pragma unroll
  for (int i = 0; i < 2; ++i) {
    const int slot = i * 256 + tid;          // 0..511 = 128 rows x 4 chunks
    const int r = slot >> 2, cl = slot & 3;
    goff[i] = r * (kN * 2) + ((cl ^ (r & 3)) << 4);
  }

  f32x4 acc[4][4] = {};

#define STAGE(kt, buf)                                                        \
  {                                                                           \
    _Pragma("unroll")                                                         \
    for (int i = 0; i < 2; ++i) {                                             \
      gload_lds16(Abase + goff[i] + (kt) * 64,                                \
                  (char*)As[buf] + (i * 256 + tid) * 16);                     \
      gload_lds16(Bbase + goff[i] + (kt) * 64,                                \
                  (char*)Bs[buf] + (i * 256 + tid) * 16);                     \
    }                                                                         \
  }

  // prologue: stage tiles 0 and 1 (8 loads in flight)
  STAGE(0, 0);
  STAGE(1, 1);

  const int NT = kN / 32;                     // 64 K-tiles
  for (int t = 0; t < NT; ++t) {
    const int cur = t % 3, nxt = (t + 2) % 3;

    // tile head: counted wait (t's 4 loads are the oldest; t+1's 4 stay in flight)
    if (t < NT - 1) asm volatile("s_waitcnt vmcnt(4)" ::: "memory");
    else            asm volatile("s_waitcnt vmcnt(0)" ::: "memory");
    __builtin_amdgcn_s_barrier();

    if (t + 2 < NT) STAGE(t + 2, nxt);        // overlaps 2 full tiles of compute
    __builtin_amdgcn_sched_barrier(0);        // pin stage-issue before compute

    const char* abuf = (const char*)As[cur];
    const char* bbuf = (const char*)Bs[cur];
    short8 af[4], bf[4];
#pragma unroll
    for (int mt = 0; mt < 4; ++mt) {
      const int row = wr * 64 + mt * 16 + r16;
      af[mt] = *(const short8*)(abuf + row * 64 + ((kg ^ (row & 3)) << 4));
    }
#pragma unroll
    for (int nt = 0; nt < 4; ++nt) {
      const int row = wc * 64 + nt * 16 + r16;
      bf[nt] = *(const short8*)(bbuf + row * 64 + ((kg ^ (row & 3)) << 4));
    }
    __builtin_amdgcn_s_setprio(1);
#pragma unroll
    for (int mt = 0; mt < 4; ++mt)
#pragma unroll
      for (int nt = 0; nt < 4; ++nt)
        acc[mt][nt] = __builtin_amdgcn_mfma_f32_16x16x32_bf16(
            af[mt], bf[nt], acc[mt][nt], 0, 0, 0);
    __builtin_amdgcn_s_setprio(0);
  }
#undef STAGE

  // epilogue: D row = (lane>>4)*4 + reg, col = lane&15 (verified layout)
#pragma unroll
  for (int mt = 0; mt < 4; ++mt)
#pragma unroll
    for (int nt = 0; nt < 4; ++nt) {
      const int r = row0 + wr * 64 + mt * 16 + kg * 4;
      const int c = col0 + wc * 64 + nt * 16 + r16;
#pragma unroll
      for (int j = 0; j < 4; ++j)
        C[(size_t)(r + j) * kN + c] = acc[mt][nt][j];
    }
}

extern "C" void kernel_launch(void* const* d_in, const int* in_sizes, int n_in,
                              void* d_out, int out_size, void* d_ws, size_t ws_size,
                              hipStream_t stream) {
  const float* x = (const float*)d_in[0];
  const float* G = (const float*)d_in[1];
  const float* H = (const float*)d_in[2];
  float* out = (float*)d_out;

  char* ws = (char*)d_ws;
  unsigned short* Mb = (unsigned short*)ws;                      // 8 MB  bf16 M[i][j]
  unsigned short* xb = (unsigned short*)(ws + (8u << 20));       // 16 MB bf16 x
  unsigned short* Dp = (unsigned short*)(ws + (24u << 20));      // 8 MB  bf16 diag-major

  const int cast_blocks = (kB * kN) / (256 * 8);                 // 4096
  prep_kernel<<<dim3(cast_blocks + kN), dim3(256), 0, stream>>>(x, G, H, xb, Dp);
  build_M_kernel<<<dim3(kN / 64, kN / 64), dim3(256), 0, stream>>>(Dp, Mb);
  gemm_kernel<<<dim3(kN / 128, kB / 128), dim3(256), 0, stream>>>(xb, Mb, out);
}